// Round 1
// 711.937 us; speedup vs baseline: 1.3808x; 1.3808x over previous
//
#include <hip/hip_runtime.h>

#define CI 4
#define CO 8
#define TT 8
#define S 96
#define SLICE (S*S*S)          // 884736 elements per (c,t) slice
#define NSLICE (CI*TT)         // 32 slices
#define EPS 1e-5f

// ws layout (floats): [0:32) sum, [32:64) sumsq  (atomic accumulators)

__global__ __launch_bounds__(256) void stats_partial(
        const float* __restrict__ x, float* __restrict__ ws) {
    const int slice = blockIdx.y;
    const float4* p = reinterpret_cast<const float4*>(x + (size_t)slice * SLICE);
    const int n4 = SLICE / 4;  // 221184
    float s = 0.f, ss = 0.f;
    for (int i = blockIdx.x * blockDim.x + threadIdx.x; i < n4;
         i += gridDim.x * blockDim.x) {
        float4 v = p[i];
        s  += v.x + v.y + v.z + v.w;
        ss += v.x*v.x + v.y*v.y + v.z*v.z + v.w*v.w;
    }
    #pragma unroll
    for (int off = 32; off > 0; off >>= 1) {
        s  += __shfl_down(s, off);
        ss += __shfl_down(ss, off);
    }
    __shared__ float ls[4], lss[4];
    const int lane = threadIdx.x & 63, wid = threadIdx.x >> 6;
    if (lane == 0) { ls[wid] = s; lss[wid] = ss; }
    __syncthreads();
    if (threadIdx.x == 0) {
        float ts  = ls[0] + ls[1] + ls[2] + ls[3];
        float tss = lss[0] + lss[1] + lss[2] + lss[3];
        atomicAdd(&ws[slice], ts);
        atomicAdd(&ws[NSLICE + slice], tss);
    }
}

// Register-blocked fused norm+relu+conv4d.
// Thread tile: 4 w (float4 chunk) x 2 h x 8 co = 64 accumulators.
// Block (24,8): 96 w x 16 h at fixed (d,t). Grid (96, 6, 8).
// Each input row loaded once per (ci,tt,dd) as dwordx4 + 2 edge scalars,
// normalized ONCE, then reused for up to 2 (h_out,kh) tap-sets x 3 kw x 8 co.
// h-edge masking folded into rstd/nmr (relu(fma(x,0,0)) == 0).
__global__ __launch_bounds__(192, 3) void conv4d_fused(
        const float* __restrict__ x, const float* __restrict__ wgt,
        const float* __restrict__ bias, const float* __restrict__ ws,
        float* __restrict__ out) {
    const int lane = threadIdx.x;          // 0..23 -> w chunk
    const int ty   = threadIdx.y;          // 0..7
    const int w0   = lane << 2;            // 0,4,...,92
    const int d    = blockIdx.x;
    const int h0   = (blockIdx.y * 8 + ty) * 2;   // first of 2 h rows
    const int t    = blockIdx.z;

    float acc[2][CO][4];
    #pragma unroll
    for (int p = 0; p < 2; p++)
        #pragma unroll
        for (int co = 0; co < CO; co++)
            #pragma unroll
            for (int j = 0; j < 4; j++) acc[p][co][j] = 0.f;

    const bool wlb = (lane > 0), wrb = (lane < 23);
    const int  om1 = wlb ? -1 : 0;         // clamped: loads always in-range
    const int  op4 = wrb ?  4 : 3;
    const float fwl = wlb ? 1.f : 0.f, fwr = wrb ? 1.f : 0.f;
    const float inv_n = 1.f / (float)SLICE;

    for (int ci = 0; ci < CI; ci++) {
        for (int kt = 0; kt < 3; kt++) {
            const int tt = t + kt - 1;
            if ((unsigned)tt >= TT) continue;          // uniform scalar branch
            const int sl = ci * TT + tt;
            const float mean = ws[sl] * inv_n;
            const float var  = ws[NSLICE + sl] * inv_n - mean * mean;
            const float rstd = rsqrtf(var + EPS);
            const float nmr  = -mean * rstd;
            const float* xs = x + (size_t)sl * SLICE;
            #pragma unroll
            for (int kd = 0; kd < 3; kd++) {
                const int dd = d + kd - 1;
                if ((unsigned)dd >= S) continue;       // uniform scalar branch
                const float* xp = xs + (size_t)dd * (S * S);
                const float* wb = wgt + (ci * 3 + kt) * 27 + kd * 9;
                #pragma unroll
                for (int r = 0; r < 4; r++) {
                    const int hh = h0 + r - 1;
                    const float mr = ((unsigned)hh < S) ? 1.f : 0.f;
                    const int hc = hh < 0 ? 0 : (hh > S - 1 ? S - 1 : hh);
                    const float* row = xp + hc * S + w0;
                    const float4 f4 = *reinterpret_cast<const float4*>(row);
                    const float e0 = row[om1];
                    const float e1 = row[op4];
                    const float rs = rstd * mr, nm = nmr * mr;  // row mask folded in
                    float n[6];
                    n[0] = fwl * fmaxf(fmaf(e0,   rs, nm), 0.f);
                    n[1] =       fmaxf(fmaf(f4.x, rs, nm), 0.f);
                    n[2] =       fmaxf(fmaf(f4.y, rs, nm), 0.f);
                    n[3] =       fmaxf(fmaf(f4.z, rs, nm), 0.f);
                    n[4] =       fmaxf(fmaf(f4.w, rs, nm), 0.f);
                    n[5] = fwr * fmaxf(fmaf(e1,   rs, nm), 0.f);

                    // row hh serves output h0+p with kh = r - p (kh in [0,3))
                    #define TAP(P, KH) do {                                       \
                        const float* wp_ = wb + (KH) * 3;                         \
                        _Pragma("unroll")                                         \
                        for (int co = 0; co < CO; co++) {                         \
                            const float* wc_ = wp_ + co * (CI * 81);              \
                            const float k0 = wc_[0], k1 = wc_[1], k2 = wc_[2];    \
                            _Pragma("unroll")                                     \
                            for (int j = 0; j < 4; j++) {                         \
                                acc[P][co][j] = fmaf(n[j],     k0, acc[P][co][j]);\
                                acc[P][co][j] = fmaf(n[j + 1], k1, acc[P][co][j]);\
                                acc[P][co][j] = fmaf(n[j + 2], k2, acc[P][co][j]);\
                            }                                                     \
                        }                                                         \
                    } while (0)

                    if (r == 0)      { TAP(0, 0); }
                    else if (r == 1) { TAP(0, 1); TAP(1, 0); }
                    else if (r == 2) { TAP(0, 2); TAP(1, 1); }
                    else             { TAP(1, 2); }
                    #undef TAP
                }
            }
        }
    }

    // out shape (1, CO, T, D, H, W); float4 stores (w0 is 16B-aligned)
    #pragma unroll
    for (int p = 0; p < 2; p++) {
        const size_t obase = (((size_t)t * S + d) * S + (h0 + p)) * S + w0;
        #pragma unroll
        for (int co = 0; co < CO; co++) {
            const float bb = bias[co];
            float4 o;
            o.x = acc[p][co][0] + bb;
            o.y = acc[p][co][1] + bb;
            o.z = acc[p][co][2] + bb;
            o.w = acc[p][co][3] + bb;
            *reinterpret_cast<float4*>(out + (size_t)co * ((size_t)TT * SLICE) + obase) = o;
        }
    }
}

extern "C" void kernel_launch(void* const* d_in, const int* in_sizes, int n_in,
                              void* d_out, int out_size, void* d_ws, size_t ws_size,
                              hipStream_t stream) {
    const float* x   = (const float*)d_in[0];
    const float* w   = (const float*)d_in[1];
    const float* b   = (const float*)d_in[2];
    float* out = (float*)d_out;
    float* ws  = (float*)d_ws;

    // zero the atomic accumulators (ws is poisoned before every launch)
    hipMemsetAsync(ws, 0, 2 * NSLICE * sizeof(float), stream);
    stats_partial<<<dim3(64, NSLICE), 256, 0, stream>>>(x, ws);
    conv4d_fused<<<dim3(S, S / 16, TT), dim3(24, 8, 1), 0, stream>>>(x, w, b, ws, out);
}

// Round 2
// 699.677 us; speedup vs baseline: 1.4050x; 1.0175x over previous
//
#include <hip/hip_runtime.h>

#define CI 4
#define CO 8
#define TT 8
#define S 96
#define SLICE (S*S*S)          // 884736 elements per (c,t) slice
#define NSLICE (CI*TT)         // 32 slices
#define EPS 1e-5f

// ws layout (floats): [0:32) sum, [32:64) sumsq  (atomic accumulators)

__global__ __launch_bounds__(256) void stats_partial(
        const float* __restrict__ x, float* __restrict__ ws) {
    const int slice = blockIdx.y;
    const float4* p = reinterpret_cast<const float4*>(x + (size_t)slice * SLICE);
    const int n4 = SLICE / 4;  // 221184
    float s = 0.f, ss = 0.f;
    for (int i = blockIdx.x * blockDim.x + threadIdx.x; i < n4;
         i += gridDim.x * blockDim.x) {
        float4 v = p[i];
        s  += v.x + v.y + v.z + v.w;
        ss += v.x*v.x + v.y*v.y + v.z*v.z + v.w*v.w;
    }
    #pragma unroll
    for (int off = 32; off > 0; off >>= 1) {
        s  += __shfl_down(s, off);
        ss += __shfl_down(ss, off);
    }
    __shared__ float ls[4], lss[4];
    const int lane = threadIdx.x & 63, wid = threadIdx.x >> 6;
    if (lane == 0) { ls[wid] = s; lss[wid] = ss; }
    __syncthreads();
    if (threadIdx.x == 0) {
        float ts  = ls[0] + ls[1] + ls[2] + ls[3];
        float tss = lss[0] + lss[1] + lss[2] + lss[3];
        atomicAdd(&ws[slice], ts);
        atomicAdd(&ws[NSLICE + slice], tss);
    }
}

// Register-blocked fused norm+relu+conv4d.
// Thread tile: 4 w (float4 chunk) x 2 h x 8 co = 64 accumulators.
// Block (24,8): 96 w x 16 h at fixed (d,t). Grid (96, 6, 8).
// vs R1: the kd-edge `continue` branch is replaced by clamp+mask (folded into
// rstd/nmr, same trick as the h edge), making the whole (ci,kt) body
// straight-line so the scheduler can pipeline kd+1's loads under kd's FMAs.
__global__ __launch_bounds__(192, 3) void conv4d_fused(
        const float* __restrict__ x, const float* __restrict__ wgt,
        const float* __restrict__ bias, const float* __restrict__ ws,
        float* __restrict__ out) {
    const int lane = threadIdx.x;          // 0..23 -> w chunk
    const int ty   = threadIdx.y;          // 0..7
    const int w0   = lane << 2;            // 0,4,...,92
    const int d    = blockIdx.x;
    const int h0   = (blockIdx.y * 8 + ty) * 2;   // first of 2 h rows
    const int t    = blockIdx.z;

    float acc[2][CO][4];
    #pragma unroll
    for (int p = 0; p < 2; p++)
        #pragma unroll
        for (int co = 0; co < CO; co++)
            #pragma unroll
            for (int j = 0; j < 4; j++) acc[p][co][j] = 0.f;

    const bool wlb = (lane > 0), wrb = (lane < 23);
    const int  om1 = wlb ? -1 : 0;         // clamped: loads always in-range
    const int  op4 = wrb ?  4 : 3;
    const float fwl = wlb ? 1.f : 0.f, fwr = wrb ? 1.f : 0.f;
    const float inv_n = 1.f / (float)SLICE;

    for (int ci = 0; ci < CI; ci++) {
        for (int kt = 0; kt < 3; kt++) {
            const int tt = t + kt - 1;
            if ((unsigned)tt >= TT) continue;      // uniform, outer: cheap
            const int sl = ci * TT + tt;
            const float mean = ws[sl] * inv_n;
            const float var  = ws[NSLICE + sl] * inv_n - mean * mean;
            const float rstd = rsqrtf(var + EPS);
            const float nmr  = -mean * rstd;
            const float* xs = x + (size_t)sl * SLICE;
            // ---- straight-line over kd (d edge handled by clamp+mask) ----
            #pragma unroll
            for (int kd = 0; kd < 3; kd++) {
                const int dd = d + kd - 1;
                const float md = ((unsigned)dd < S) ? 1.f : 0.f;
                const int dc = dd < 0 ? 0 : (dd > S - 1 ? S - 1 : dd);
                const float* xp = xs + (size_t)dc * (S * S);
                const float* wb = wgt + (ci * 3 + kt) * 27 + kd * 9;

                // load + normalize all 4 rows of this kd up front
                float n[4][6];
                #pragma unroll
                for (int r = 0; r < 4; r++) {
                    const int hh = h0 + r - 1;
                    const float m_ = (((unsigned)hh < S) ? 1.f : 0.f) * md;
                    const int hc = hh < 0 ? 0 : (hh > S - 1 ? S - 1 : hh);
                    const float* row = xp + hc * S + w0;
                    const float4 f4 = *reinterpret_cast<const float4*>(row);
                    const float e0 = row[om1];
                    const float e1 = row[op4];
                    const float rs = rstd * m_, nm = nmr * m_;
                    n[r][0] = fwl * fmaxf(fmaf(e0,   rs, nm), 0.f);
                    n[r][1] =       fmaxf(fmaf(f4.x, rs, nm), 0.f);
                    n[r][2] =       fmaxf(fmaf(f4.y, rs, nm), 0.f);
                    n[r][3] =       fmaxf(fmaf(f4.z, rs, nm), 0.f);
                    n[r][4] =       fmaxf(fmaf(f4.w, rs, nm), 0.f);
                    n[r][5] = fwr * fmaxf(fmaf(e1,   rs, nm), 0.f);
                }

                // row hh = h0+r-1 serves output h0+p with kh = r - p
                #define TAP(P, KH, NR) do {                                   \
                    const float* wp_ = wb + (KH) * 3;                         \
                    _Pragma("unroll")                                         \
                    for (int co = 0; co < CO; co++) {                         \
                        const float* wc_ = wp_ + co * (CI * 81);              \
                        const float k0 = wc_[0], k1 = wc_[1], k2 = wc_[2];    \
                        _Pragma("unroll")                                     \
                        for (int j = 0; j < 4; j++) {                         \
                            acc[P][co][j] = fmaf(NR[j],     k0, acc[P][co][j]);\
                            acc[P][co][j] = fmaf(NR[j + 1], k1, acc[P][co][j]);\
                            acc[P][co][j] = fmaf(NR[j + 2], k2, acc[P][co][j]);\
                        }                                                     \
                    }                                                         \
                } while (0)

                TAP(0, 0, n[0]);
                TAP(0, 1, n[1]); TAP(1, 0, n[1]);
                TAP(0, 2, n[2]); TAP(1, 1, n[2]);
                TAP(1, 2, n[3]);
                #undef TAP
            }
        }
    }

    // out shape (1, CO, T, D, H, W); float4 stores (w0 is 16B-aligned)
    #pragma unroll
    for (int p = 0; p < 2; p++) {
        const size_t obase = (((size_t)t * S + d) * S + (h0 + p)) * S + w0;
        #pragma unroll
        for (int co = 0; co < CO; co++) {
            const float bb = bias[co];
            float4 o;
            o.x = acc[p][co][0] + bb;
            o.y = acc[p][co][1] + bb;
            o.z = acc[p][co][2] + bb;
            o.w = acc[p][co][3] + bb;
            *reinterpret_cast<float4*>(out + (size_t)co * ((size_t)TT * SLICE) + obase) = o;
        }
    }
}

extern "C" void kernel_launch(void* const* d_in, const int* in_sizes, int n_in,
                              void* d_out, int out_size, void* d_ws, size_t ws_size,
                              hipStream_t stream) {
    const float* x   = (const float*)d_in[0];
    const float* w   = (const float*)d_in[1];
    const float* b   = (const float*)d_in[2];
    float* out = (float*)d_out;
    float* ws  = (float*)d_ws;

    // zero the atomic accumulators (ws is poisoned before every launch)
    hipMemsetAsync(ws, 0, 2 * NSLICE * sizeof(float), stream);
    stats_partial<<<dim3(64, NSLICE), 256, 0, stream>>>(x, ws);
    conv4d_fused<<<dim3(S, S / 16, TT), dim3(24, 8, 1), 0, stream>>>(x, w, b, ws, out);
}